// Round 6
// baseline (90.801 us; speedup 1.0000x reference)
//
#include <hip/hip_runtime.h>

// BoundaryLoss: mean(sigmoid(logits) * EDT2D(target)), B=8, H=W=256.
//
// Structure: 2 dispatches (fused row+column pass, final reduce).
// Session evidence:
//  - timed window = 256 MiB harness poison fill (~41 us, untouchable)
//    + kernel bodies + ~5-7 us per dispatch gap.
//  - grid.sync / threadfence+ticket cost >> a dispatch boundary (round 2).
//  - round 5: per-thread row-sequential target loads are fully uncoalesced
//    (64 lines per wave-load) -> +18 us. THIS version loads the target image
//    coalesced (lane-consecutive int4) and assembles row bitmasks in LDS via
//    a 3-step __shfl_xor OR-butterfly (8 lines per wave-load, 8x fewer).
//
// Fused pass: block -> (batch b, 4 columns w0..w0+3).
//   Phase A: build u32 bitmask smask[row][word] of target>0 in LDS (9-padded,
//            conflict-free), coalesced loads. Thread t then reads row t's
//            256-bit mask and gets the EXACT integer row distance for the 4
//            columns via clz/ffs + incremental update (bit-identical to the
//            wave-scan row kernel; empty row -> fl(1e12)). q = t^2 + d^2.
//   Phase B: O(H^2) column EDT (strength-reduced min_j j^2+m_j-2ij, q in
//            LDS, broadcast ds_read_b128 feeds 16 fma+min per float4),
//            sigmoid weighting, block reduce.
// Final kernel: deterministic 512-term reduce in the exact reference fp order.

#define BIGF 1000000.0f
#define BIG2 (BIGF * BIGF)   // fp32 rounding of 1e12, same as ref's BIG*BIG
#define BIGI (1 << 20)

constexpr int B = 8;
constexpr int H = 256;
constexpr int W = 256;
constexpr int NPIX = B * H * W;   // 524288

__device__ __forceinline__ float block_reduce_sum_256(float v) {
    #pragma unroll
    for (int off = 32; off > 0; off >>= 1)
        v += __shfl_down(v, off, 64);
    __shared__ float s[4];
    const int lane = threadIdx.x & 63;
    const int wid  = threadIdx.x >> 6;
    if (lane == 0) s[wid] = v;
    __syncthreads();
    if (wid == 0) {
        v = (lane < 4) ? s[lane] : 0.0f;
        v += __shfl_down(v, 2, 64);
        v += __shfl_down(v, 1, 64);
    }
    return v;  // valid on thread 0
}

// 16 candidates (4 outputs x 4 j's) per LDS float4.
__device__ __forceinline__ void upd16(const float4 m, float j0,
                                      float n0, float n1, float n2, float n3,
                                      float& b0, float& b1, float& b2, float& b3) {
    const float j1 = j0 + 1.0f, j2 = j0 + 2.0f, j3 = j0 + 3.0f;
    {
        const float c0 = fmaf(n0, j0, m.x), c1 = fmaf(n0, j1, m.y);
        const float c2 = fmaf(n0, j2, m.z), c3 = fmaf(n0, j3, m.w);
        b0 = fminf(b0, fminf(fminf(c0, c1), fminf(c2, c3)));
    }
    {
        const float c0 = fmaf(n1, j0, m.x), c1 = fmaf(n1, j1, m.y);
        const float c2 = fmaf(n1, j2, m.z), c3 = fmaf(n1, j3, m.w);
        b1 = fminf(b1, fminf(fminf(c0, c1), fminf(c2, c3)));
    }
    {
        const float c0 = fmaf(n2, j0, m.x), c1 = fmaf(n2, j1, m.y);
        const float c2 = fmaf(n2, j2, m.z), c3 = fmaf(n2, j3, m.w);
        b2 = fminf(b2, fminf(fminf(c0, c1), fminf(c2, c3)));
    }
    {
        const float c0 = fmaf(n3, j0, m.x), c1 = fmaf(n3, j1, m.y);
        const float c2 = fmaf(n3, j2, m.z), c3 = fmaf(n3, j3, m.w);
        b3 = fminf(b3, fminf(fminf(c0, c1), fminf(c2, c3)));
    }
}

// Fused pass: 512 blocks x 256 thr; block -> (batch b, columns w0..w0+3).
__global__ __launch_bounds__(256) void fused_pass_kernel(
        const float* __restrict__ logits, const int* __restrict__ target,
        float* __restrict__ partials) {
    __shared__ unsigned s_mask[256][9];   // [row][word32], +1 pad: bank-free
    __shared__ float s_q[4][256];
    const int t    = threadIdx.x;
    const int lane = t & 63;
    const int wv   = t >> 6;
    const int b    = blockIdx.x >> 6;
    const int w0   = (blockIdx.x & 63) << 2;

    // ---- Phase A1: coalesced bitmask build ----
    // Chunk c: thread t loads int4 #(c*256+t) of the batch image (lane-
    // consecutive -> coalesced). Wave wv covers row 4c+wv; lane l holds the
    // nibble for cols 4l..4l+3. 3-step shfl-xor OR within 8-lane groups
    // assembles u32 words; lane l&7==0 writes word l>>3 of the row.
    {
        const int4* img4 = (const int4*)(target + b * (H * W));
        const int sh = (lane & 7) << 2;   // nibble position in the u32 word
        const int w8 = lane >> 3;         // word this 8-lane group owns
        #pragma unroll 8
        for (int c = 0; c < 64; ++c) {
            const int4 tv = img4[(c << 8) + t];
            int v = (tv.x > 0 ? 1 : 0) | (tv.y > 0 ? 2 : 0)
                  | (tv.z > 0 ? 4 : 0) | (tv.w > 0 ? 8 : 0);
            v <<= sh;
            v |= __shfl_xor(v, 1, 64);
            v |= __shfl_xor(v, 2, 64);
            v |= __shfl_xor(v, 4, 64);
            if ((lane & 7) == 0) s_mask[(c << 2) + wv][w8] = (unsigned)v;
        }
    }
    __syncthreads();

    // ---- Phase A2: row-t distances via clz/ffs on the 256-bit mask ----
    {
        unsigned long long wb[4];
        #pragma unroll
        for (int g = 0; g < 4; ++g)
            wb[g] = (unsigned long long)s_mask[t][2 * g]
                  | ((unsigned long long)s_mask[t][2 * g + 1] << 32);

        // nearest set bit <= w0 (L) and >= w0+3 (R3); exact, branchless.
        const int kw     = w0 >> 6;                    // wave-uniform 0..3
        const int bshift = w0 & 63;                    // wave-uniform, <= 60
        const unsigned long long mlo = (2ull << bshift) - 1ull;   // bits 0..bshift
        const unsigned long long mhi = (~0ull) << (bshift + 3);   // bits bshift+3..

        int L = -BIGI;
        #pragma unroll
        for (int k = 0; k < 4; ++k) {   // ascending: later nonzero word wins
            const unsigned long long vl =
                (k < kw) ? wb[k] : ((k == kw) ? (wb[k] & mlo) : 0ull);
            const int candL = (k << 6) + 63 - __clzll((long long)vl);
            L = vl ? candL : L;
        }
        int R3 = BIGI;
        #pragma unroll
        for (int k = 3; k >= 0; --k) {  // descending: smaller nonzero word wins
            const unsigned long long vr =
                (k > kw) ? wb[k] : ((k == kw) ? (wb[k] & mhi) : 0ull);
            const int candR = (k << 6) + __ffsll((unsigned long long)vr) - 1;
            R3 = vr ? candR : R3;
        }

        // incremental across the 4 adjacent columns (all in word kw)
        const unsigned long long wkw =
            (kw & 2) ? ((kw & 1) ? wb[3] : wb[2]) : ((kw & 1) ? wb[1] : wb[0]);
        const unsigned bit0 = (unsigned)(wkw >> bshift)       & 1u;
        const unsigned bit1 = (unsigned)(wkw >> (bshift + 1)) & 1u;
        const unsigned bit2 = (unsigned)(wkw >> (bshift + 2)) & 1u;
        const unsigned bit3 = (unsigned)(wkw >> (bshift + 3)) & 1u;

        const int L0 = L;                        // L(w0) (includes bit w0)
        const int L1 = bit1 ? (w0 + 1) : L0;
        const int L2 = bit2 ? (w0 + 2) : L1;
        const int L3 = bit3 ? (w0 + 3) : L2;
        const int R3c = R3;                      // R(w0+3)
        const int R2 = bit2 ? (w0 + 2) : R3c;
        const int R1 = bit1 ? (w0 + 1) : R2;
        const int R0 = bit0 ? (w0 + 0) : R1;

        const int d0 = min(w0     - L0, R0 - w0);
        const int d1 = min(w0 + 1 - L1, R1 - (w0 + 1));
        const int d2 = min(w0 + 2 - L2, R2 - (w0 + 2));
        const int d3 = min(w0 + 3 - L3, R3c - (w0 + 3));

        const float fj  = (float)t;
        const float fj2 = fj * fj;               // exact (< 2^24)
        const float f0 = (float)d0, f1 = (float)d1;
        const float f2 = (float)d2, f3 = (float)d3;
        s_q[0][t] = fj2 + ((d0 > 255) ? BIG2 : f0 * f0);
        s_q[1][t] = fj2 + ((d1 > 255) ? BIG2 : f1 * f1);
        s_q[2][t] = fj2 + ((d2 > 255) ? BIG2 : f2 * f2);
        s_q[3][t] = fj2 + ((d3 > 255) ? BIG2 : f3 * f3);
    }
    __syncthreads();

    // ---- Phase B: column EDT + sigmoid + block reduce (unchanged) ----
    const float i0f = (float)lane,         i1f = (float)(lane + 64);
    const float i2f = (float)(lane + 128), i3f = (float)(lane + 192);
    const float n0 = -2.0f * i0f, n1 = -2.0f * i1f;
    const float n2 = -2.0f * i2f, n3 = -2.0f * i3f;
    float b0 = 4e12f, b1 = 4e12f, b2 = 4e12f, b3 = 4e12f;

    float fjv = 0.0f;
    #pragma unroll 4
    for (int jv = 0; jv < 64; ++jv, fjv += 4.0f) {
        const float4 m = *(const float4*)&s_q[wv][jv << 2];
        upd16(m, fjv, n0, n1, n2, n3, b0, b1, b2, b3);
    }

    const int wcol = w0 + wv;
    const int base = (b * H + lane) * W + wcol;
    float acc;
    {
        const float dist = sqrtf(fmaf(i0f, i0f, b0));
        const float x = logits[base];
        acc = dist / (1.0f + expf(-x));
    }
    {
        const float dist = sqrtf(fmaf(i1f, i1f, b1));
        const float x = logits[base + 64 * W];
        acc += dist / (1.0f + expf(-x));
    }
    {
        const float dist = sqrtf(fmaf(i2f, i2f, b2));
        const float x = logits[base + 128 * W];
        acc += dist / (1.0f + expf(-x));
    }
    {
        const float dist = sqrtf(fmaf(i3f, i3f, b3));
        const float x = logits[base + 192 * W];
        acc += dist / (1.0f + expf(-x));
    }

    const float s = block_reduce_sum_256(acc);
    if (t == 0) partials[blockIdx.x] = s;
}

__global__ __launch_bounds__(256) void final_reduce_kernel(
        const float* __restrict__ partials, float* __restrict__ out,
        int n, float scale) {
    float v = 0.0f;
    for (int idx = threadIdx.x; idx < n; idx += 256)
        v += partials[idx];
    v = block_reduce_sum_256(v);
    if (threadIdx.x == 0) out[0] = v * scale;
}

extern "C" void kernel_launch(void* const* d_in, const int* in_sizes, int n_in,
                              void* d_out, int out_size, void* d_ws, size_t ws_size,
                              hipStream_t stream) {
    const float* logits = (const float*)d_in[0];
    const int*   target = (const int*)d_in[1];

    float* partials = (float*)d_ws;     // 512 floats

    fused_pass_kernel<<<B * W / 4, 256, 0, stream>>>(logits, target, partials);
    final_reduce_kernel<<<1, 256, 0, stream>>>(partials, (float*)d_out,
                                               B * W / 4, 1.0f / (float)NPIX);
}

// Round 7
// 72.781 us; speedup vs baseline: 1.2476x; 1.2476x over previous
//
#include <hip/hip_runtime.h>

// BoundaryLoss: mean(sigmoid(logits) * EDT2D(target)), B=8, H=W=256.
//
// Structure: 2 dispatches (row pass; column pass with in-kernel final reduce).
// Session evidence (rounds 0-6):
//  - timed window = 256 MiB harness poison fill (~41 us) + ~15 us fill-drain
//    gap (untouchable) + ~3-4 us per additional dispatch + kernel bodies.
//  - col pass is at its VALU issue floor (3.4 us computed ~= 3.5 measured).
//  - fusing row into col via per-block image rebuild costs 25-30 us (rounds
//    5/6) -> dead. grid.sync costs ~50 us (round 2) -> dead.
//  - __threadfence() per block = full L2 writeback (round 1, +10 us) -> dead.
//  - THIS round: fold the final reduce into the col pass WITHOUT fences:
//    agent-scope relaxed atomic store of the partial (lands at the L3
//    coherence point, no L2 writeback) + s_waitcnt vmcnt(0) ordering +
//    relaxed agent-scope ticket; last block reads partials with agent-scope
//    atomic loads (bypass stale per-XCD L2). Deterministic fp order kept
//    identical to the old final_reduce_kernel -> absmax stays 0.0.
//
// Pass 1: O(W) row 1D-distance via wave max/min scans (exact ints; empty row
//         -> fl(1e12)); also resets the ticket counter.
// Pass 2: column EDT (strength-reduced min_j j^2+m_j-2ij, q staged in LDS,
//         broadcast ds_read_b128 feeds 16 fma+min per float4) + sigmoid
//         weighting + block reduce + fence-free last-block final reduce.

#define BIGF 1000000.0f
#define BIG2 (BIGF * BIGF)   // fp32 rounding of 1e12, same as ref's BIG*BIG
#define BIGI (1 << 20)

constexpr int B = 8;
constexpr int H = 256;
constexpr int W = 256;
constexpr int NPIX = B * H * W;   // 524288
constexpr int NBLK = B * W / 4;   // 512 col-pass blocks

__device__ __forceinline__ float block_reduce_sum_256(float v) {
    #pragma unroll
    for (int off = 32; off > 0; off >>= 1)
        v += __shfl_down(v, off, 64);
    __shared__ float s[4];
    const int lane = threadIdx.x & 63;
    const int wid  = threadIdx.x >> 6;
    if (lane == 0) s[wid] = v;
    __syncthreads();
    if (wid == 0) {
        v = (lane < 4) ? s[lane] : 0.0f;
        v += __shfl_down(v, 2, 64);
        v += __shfl_down(v, 1, 64);
    }
    return v;  // valid on thread 0
}

// 16 candidates (4 outputs x 4 j's) per LDS float4.
__device__ __forceinline__ void upd16(const float4 m, float j0,
                                      float n0, float n1, float n2, float n3,
                                      float& b0, float& b1, float& b2, float& b3) {
    const float j1 = j0 + 1.0f, j2 = j0 + 2.0f, j3 = j0 + 3.0f;
    {
        const float c0 = fmaf(n0, j0, m.x), c1 = fmaf(n0, j1, m.y);
        const float c2 = fmaf(n0, j2, m.z), c3 = fmaf(n0, j3, m.w);
        b0 = fminf(b0, fminf(fminf(c0, c1), fminf(c2, c3)));
    }
    {
        const float c0 = fmaf(n1, j0, m.x), c1 = fmaf(n1, j1, m.y);
        const float c2 = fmaf(n1, j2, m.z), c3 = fmaf(n1, j3, m.w);
        b1 = fminf(b1, fminf(fminf(c0, c1), fminf(c2, c3)));
    }
    {
        const float c0 = fmaf(n2, j0, m.x), c1 = fmaf(n2, j1, m.y);
        const float c2 = fmaf(n2, j2, m.z), c3 = fmaf(n2, j3, m.w);
        b2 = fminf(b2, fminf(fminf(c0, c1), fminf(c2, c3)));
    }
    {
        const float c0 = fmaf(n3, j0, m.x), c1 = fmaf(n3, j1, m.y);
        const float c2 = fmaf(n3, j2, m.z), c3 = fmaf(n3, j3, m.w);
        b3 = fminf(b3, fminf(fminf(c0, c1), fminf(c2, c3)));
    }
}

// Pass 1: row squared-distances via wave scans. 512 blocks x 256 thr;
// wave wv handles row blk*4+wv, lane L owns pixels 4L..4L+3.
__global__ __launch_bounds__(256) void row_dist_kernel(
        const int* __restrict__ target, float* __restrict__ dr2,
        unsigned* __restrict__ counter) {
    const int lane = threadIdx.x & 63;
    const int wv   = threadIdx.x >> 6;
    const int row  = (blockIdx.x << 2) + wv;

    // reset the ticket (poisoned by the harness fill). Agent-scope store ->
    // lands at the L3 coherence point; visible to pass 2's sc1 atomics.
    if (blockIdx.x == 0 && threadIdx.x == 0)
        __hip_atomic_store(counter, 0u, __ATOMIC_RELAXED,
                           __HIP_MEMORY_SCOPE_AGENT);

    const int4 tv = *(const int4*)(target + row * W + (lane << 2));
    const int i0 = lane << 2;

    // ---- left scan: nearest fg index <= p ----
    int lastL = -1;                      // lane-local last fg idx
    if (tv.x > 0) lastL = i0;
    if (tv.y > 0) lastL = i0 + 1;
    if (tv.z > 0) lastL = i0 + 2;
    if (tv.w > 0) lastL = i0 + 3;
    int incl = lastL;
    #pragma unroll
    for (int off = 1; off < 64; off <<= 1) {
        const int x = __shfl_up(incl, off, 64);
        if (lane >= off) incl = max(incl, x);
    }
    int runL = __shfl_up(incl, 1, 64);
    if (lane == 0) runL = -1;            // exclusive prefix

    if (tv.x > 0) runL = i0;
    const int dl0 = (runL >= 0) ? (i0     - runL) : BIGI;
    if (tv.y > 0) runL = i0 + 1;
    const int dl1 = (runL >= 0) ? (i0 + 1 - runL) : BIGI;
    if (tv.z > 0) runL = i0 + 2;
    const int dl2 = (runL >= 0) ? (i0 + 2 - runL) : BIGI;
    if (tv.w > 0) runL = i0 + 3;
    const int dl3 = (runL >= 0) ? (i0 + 3 - runL) : BIGI;

    // ---- right scan: nearest fg index >= p ----
    int nextR = BIGI;                    // lane-local first fg idx
    if (tv.w > 0) nextR = i0 + 3;
    if (tv.z > 0) nextR = i0 + 2;
    if (tv.y > 0) nextR = i0 + 1;
    if (tv.x > 0) nextR = i0;
    int inclR = nextR;
    #pragma unroll
    for (int off = 1; off < 64; off <<= 1) {
        const int x = __shfl_down(inclR, off, 64);
        if (lane < 64 - off) inclR = min(inclR, x);
    }
    int runR = __shfl_down(inclR, 1, 64);
    if (lane == 63) runR = BIGI;         // exclusive suffix

    if (tv.w > 0) runR = i0 + 3;
    const int dR3 = runR - (i0 + 3);
    if (tv.z > 0) runR = i0 + 2;
    const int dR2v = runR - (i0 + 2);
    if (tv.y > 0) runR = i0 + 1;
    const int dR1 = runR - (i0 + 1);
    if (tv.x > 0) runR = i0;
    const int dR0 = runR - i0;

    // ---- combine, square (exact ints < 2^24), coalesced float4 store ----
    const int d0 = min(dl0, dR0), d1 = min(dl1, dR1);
    const int d2 = min(dl2, dR2v), d3 = min(dl3, dR3);
    const float f0 = (float)d0, f1 = (float)d1, f2 = (float)d2, f3 = (float)d3;
    float4 o;
    o.x = (d0 > 255) ? BIG2 : f0 * f0;
    o.y = (d1 > 255) ? BIG2 : f1 * f1;
    o.z = (d2 > 255) ? BIG2 : f2 * f2;
    o.w = (d3 > 255) ? BIG2 : f3 * f3;
    *(float4*)(dr2 + row * W + (lane << 2)) = o;
}

// Pass 2: column EDT + sqrt + sigmoid + per-block reduce + fence-free
// last-block final reduce. 512 blocks x 256 thr.
__global__ __launch_bounds__(256) void col_pass_kernel(
        const float* __restrict__ logits, const float* __restrict__ dr2,
        float* __restrict__ partials, unsigned* __restrict__ counter,
        float* __restrict__ out) {
    __shared__ float s_q[4][256];
    __shared__ unsigned s_prev;
    const int t  = threadIdx.x;
    const int b  = blockIdx.x >> 6;
    const int w0 = (blockIdx.x & 63) << 2;

    // stage q_j = j^2 + dr2[j][w0+c]; thread t handles j = t (float4 per thread)
    const float4 v  = *(const float4*)(dr2 + (b * H + t) * W + w0);
    const float fj  = (float)t;
    const float fj2 = fj * fj;              // exact (< 2^24)
    s_q[0][t] = fj2 + v.x;
    s_q[1][t] = fj2 + v.y;
    s_q[2][t] = fj2 + v.z;
    s_q[3][t] = fj2 + v.w;
    __syncthreads();

    const int lane = t & 63;
    const int wv   = t >> 6;
    const float i0f = (float)lane,         i1f = (float)(lane + 64);
    const float i2f = (float)(lane + 128), i3f = (float)(lane + 192);
    const float n0 = -2.0f * i0f, n1 = -2.0f * i1f;
    const float n2 = -2.0f * i2f, n3 = -2.0f * i3f;
    float b0 = 4e12f, b1 = 4e12f, b2 = 4e12f, b3 = 4e12f;

    float fjv = 0.0f;
    #pragma unroll 4
    for (int jv = 0; jv < 64; ++jv, fjv += 4.0f) {
        const float4 m = *(const float4*)&s_q[wv][jv << 2];
        upd16(m, fjv, n0, n1, n2, n3, b0, b1, b2, b3);
    }

    const int wcol = w0 + wv;
    const int base = (b * H + lane) * W + wcol;
    float acc;
    {
        const float dist = sqrtf(fmaf(i0f, i0f, b0));
        const float x = logits[base];
        acc = dist / (1.0f + expf(-x));
    }
    {
        const float dist = sqrtf(fmaf(i1f, i1f, b1));
        const float x = logits[base + 64 * W];
        acc += dist / (1.0f + expf(-x));
    }
    {
        const float dist = sqrtf(fmaf(i2f, i2f, b2));
        const float x = logits[base + 128 * W];
        acc += dist / (1.0f + expf(-x));
    }
    {
        const float dist = sqrtf(fmaf(i3f, i3f, b3));
        const float x = logits[base + 192 * W];
        acc += dist / (1.0f + expf(-x));
    }

    const float s = block_reduce_sum_256(acc);

    // ---- fence-free last-block final reduction ----
    // Partial store is an agent-scope relaxed atomic (sc1 -> L3 coherence
    // point, NO L2 writeback). s_waitcnt vmcnt(0) guarantees it completed
    // before the ticket increments (both serialize at L3). Last block reads
    // all partials with agent-scope atomic loads (bypass stale per-XCD L2).
    if (t == 0) {
        __hip_atomic_store(&partials[blockIdx.x], s, __ATOMIC_RELAXED,
                           __HIP_MEMORY_SCOPE_AGENT);
        asm volatile("s_waitcnt vmcnt(0)" ::: "memory");
        s_prev = __hip_atomic_fetch_add(counter, 1u, __ATOMIC_RELAXED,
                                        __HIP_MEMORY_SCOPE_AGENT);
    }
    __syncthreads();   // broadcasts s_prev; also makes s_q/s[] reuse safe
    if (s_prev == NBLK - 1) {
        // exact same fp order as the old final_reduce_kernel:
        // v = (0 + partials[t]) + partials[t+256], then the same block tree.
        float fv = __hip_atomic_load(&partials[t], __ATOMIC_RELAXED,
                                     __HIP_MEMORY_SCOPE_AGENT);
        fv += __hip_atomic_load(&partials[t + 256], __ATOMIC_RELAXED,
                                __HIP_MEMORY_SCOPE_AGENT);
        const float tot = block_reduce_sum_256(fv);
        if (t == 0) out[0] = tot * (1.0f / (float)NPIX);
    }
}

extern "C" void kernel_launch(void* const* d_in, const int* in_sizes, int n_in,
                              void* d_out, int out_size, void* d_ws, size_t ws_size,
                              hipStream_t stream) {
    const float* logits = (const float*)d_in[0];
    const int*   target = (const int*)d_in[1];

    float*    dr2      = (float*)d_ws;      // NPIX floats (2 MB)
    float*    partials = dr2 + NPIX;        // 512 floats
    unsigned* counter  = (unsigned*)(partials + 512);

    row_dist_kernel<<<B * H / 4, 256, 0, stream>>>(target, dr2, counter);
    col_pass_kernel<<<NBLK, 256, 0, stream>>>(logits, dr2, partials,
                                              counter, (float*)d_out);
}

// Round 8
// 71.027 us; speedup vs baseline: 1.2784x; 1.0247x over previous
//
#include <hip/hip_runtime.h>

// BoundaryLoss: mean(sigmoid(logits) * EDT2D(target)), B=8, H=W=256.
//
// FINAL structure: 3 dispatches (row pass, column pass, final reduce).
// Session price list (rounds 0-7, all measured):
//  - 256 MiB harness poison fill: ~41-42 us, unconditional (present even
//    when only 512 B of workspace is used) -> untouchable floor.
//  - fill->first-kernel drain gap: ~15 us, harness/memory-system -> untouchable.
//  - grid.sync: ~50 us per sync (8-XCD L2 coherence) -> dead.
//  - per-block __threadfence(): +10 us (full L2 writeback) -> dead.
//  - fusing row pass into col pass via per-block image rebuild: +18..25 us
//    (redundant traffic + cross-lane ops) -> dead.
//  - fence-free last-block reduce (agent-scope atomics): neutral (+-1 us);
//    the trailing tiny dispatch's gap is already hidden by the command
//    processor pipelining -> keep the simpler 3-kernel form.
//  - col pass is at its VALU issue floor (3.4 us computed ~= 3.5 measured);
//    row pass ~1.5 us via O(W) wave scans (vs 3.5 brute force).
// Total ~70 us = ~63 us fixed overhead + ~7 us of kernel bodies.
//
// Pass 1: O(W) row 1D-distance via wave max/min scans (exact integer
//         distances -> bit-identical to ref; empty row -> fl(1e12)).
// Pass 2: column EDT: strength-reduced min_j (i-j)^2+m_j = i^2+min_j(j^2+
//         m_j-2ij); q_j staged in LDS, broadcast ds_read_b128 feeds 16
//         fma+min per float4; + sigmoid weighting + block reduce.
// Pass 3: 512-term deterministic reduce (exact reference fp order).

#define BIGF 1000000.0f
#define BIG2 (BIGF * BIGF)   // fp32 rounding of 1e12, same as ref's BIG*BIG
#define BIGI (1 << 20)

constexpr int B = 8;
constexpr int H = 256;
constexpr int W = 256;
constexpr int NPIX = B * H * W;   // 524288

__device__ __forceinline__ float block_reduce_sum_256(float v) {
    #pragma unroll
    for (int off = 32; off > 0; off >>= 1)
        v += __shfl_down(v, off, 64);
    __shared__ float s[4];
    const int lane = threadIdx.x & 63;
    const int wid  = threadIdx.x >> 6;
    if (lane == 0) s[wid] = v;
    __syncthreads();
    if (wid == 0) {
        v = (lane < 4) ? s[lane] : 0.0f;
        v += __shfl_down(v, 2, 64);
        v += __shfl_down(v, 1, 64);
    }
    return v;  // valid on thread 0
}

// 16 candidates (4 outputs x 4 j's) per LDS float4.
__device__ __forceinline__ void upd16(const float4 m, float j0,
                                      float n0, float n1, float n2, float n3,
                                      float& b0, float& b1, float& b2, float& b3) {
    const float j1 = j0 + 1.0f, j2 = j0 + 2.0f, j3 = j0 + 3.0f;
    {
        const float c0 = fmaf(n0, j0, m.x), c1 = fmaf(n0, j1, m.y);
        const float c2 = fmaf(n0, j2, m.z), c3 = fmaf(n0, j3, m.w);
        b0 = fminf(b0, fminf(fminf(c0, c1), fminf(c2, c3)));
    }
    {
        const float c0 = fmaf(n1, j0, m.x), c1 = fmaf(n1, j1, m.y);
        const float c2 = fmaf(n1, j2, m.z), c3 = fmaf(n1, j3, m.w);
        b1 = fminf(b1, fminf(fminf(c0, c1), fminf(c2, c3)));
    }
    {
        const float c0 = fmaf(n2, j0, m.x), c1 = fmaf(n2, j1, m.y);
        const float c2 = fmaf(n2, j2, m.z), c3 = fmaf(n2, j3, m.w);
        b2 = fminf(b2, fminf(fminf(c0, c1), fminf(c2, c3)));
    }
    {
        const float c0 = fmaf(n3, j0, m.x), c1 = fmaf(n3, j1, m.y);
        const float c2 = fmaf(n3, j2, m.z), c3 = fmaf(n3, j3, m.w);
        b3 = fminf(b3, fminf(fminf(c0, c1), fminf(c2, c3)));
    }
}

// Pass 1: row squared-distances via wave scans. 512 blocks x 256 thr;
// wave wv handles row blk*4+wv, lane L owns pixels 4L..4L+3.
__global__ __launch_bounds__(256) void row_dist_kernel(
        const int* __restrict__ target, float* __restrict__ dr2) {
    const int lane = threadIdx.x & 63;
    const int wv   = threadIdx.x >> 6;
    const int row  = (blockIdx.x << 2) + wv;

    const int4 tv = *(const int4*)(target + row * W + (lane << 2));
    const int i0 = lane << 2;

    // ---- left scan: nearest fg index <= p ----
    int lastL = -1;                      // lane-local last fg idx
    if (tv.x > 0) lastL = i0;
    if (tv.y > 0) lastL = i0 + 1;
    if (tv.z > 0) lastL = i0 + 2;
    if (tv.w > 0) lastL = i0 + 3;
    int incl = lastL;
    #pragma unroll
    for (int off = 1; off < 64; off <<= 1) {
        const int x = __shfl_up(incl, off, 64);
        if (lane >= off) incl = max(incl, x);
    }
    int runL = __shfl_up(incl, 1, 64);
    if (lane == 0) runL = -1;            // exclusive prefix

    if (tv.x > 0) runL = i0;
    const int dl0 = (runL >= 0) ? (i0     - runL) : BIGI;
    if (tv.y > 0) runL = i0 + 1;
    const int dl1 = (runL >= 0) ? (i0 + 1 - runL) : BIGI;
    if (tv.z > 0) runL = i0 + 2;
    const int dl2 = (runL >= 0) ? (i0 + 2 - runL) : BIGI;
    if (tv.w > 0) runL = i0 + 3;
    const int dl3 = (runL >= 0) ? (i0 + 3 - runL) : BIGI;

    // ---- right scan: nearest fg index >= p ----
    int nextR = BIGI;                    // lane-local first fg idx
    if (tv.w > 0) nextR = i0 + 3;
    if (tv.z > 0) nextR = i0 + 2;
    if (tv.y > 0) nextR = i0 + 1;
    if (tv.x > 0) nextR = i0;
    int inclR = nextR;
    #pragma unroll
    for (int off = 1; off < 64; off <<= 1) {
        const int x = __shfl_down(inclR, off, 64);
        if (lane < 64 - off) inclR = min(inclR, x);
    }
    int runR = __shfl_down(inclR, 1, 64);
    if (lane == 63) runR = BIGI;         // exclusive suffix

    if (tv.w > 0) runR = i0 + 3;
    const int dR3 = runR - (i0 + 3);
    if (tv.z > 0) runR = i0 + 2;
    const int dR2v = runR - (i0 + 2);
    if (tv.y > 0) runR = i0 + 1;
    const int dR1 = runR - (i0 + 1);
    if (tv.x > 0) runR = i0;
    const int dR0 = runR - i0;

    // ---- combine, square (exact ints < 2^24), coalesced float4 store ----
    const int d0 = min(dl0, dR0), d1 = min(dl1, dR1);
    const int d2 = min(dl2, dR2v), d3 = min(dl3, dR3);
    const float f0 = (float)d0, f1 = (float)d1, f2 = (float)d2, f3 = (float)d3;
    float4 o;
    o.x = (d0 > 255) ? BIG2 : f0 * f0;
    o.y = (d1 > 255) ? BIG2 : f1 * f1;
    o.z = (d2 > 255) ? BIG2 : f2 * f2;
    o.w = (d3 > 255) ? BIG2 : f3 * f3;
    *(float4*)(dr2 + row * W + (lane << 2)) = o;
}

// Pass 2: column EDT + sqrt + sigmoid + per-block reduce.
// 512 blocks x 256 thr; block -> (batch b, columns w0..w0+3); wave c -> col.
__global__ __launch_bounds__(256) void col_pass_kernel(
        const float* __restrict__ logits, const float* __restrict__ dr2,
        float* __restrict__ partials) {
    __shared__ float s_q[4][256];
    const int t  = threadIdx.x;
    const int b  = blockIdx.x >> 6;
    const int w0 = (blockIdx.x & 63) << 2;

    // stage q_j = j^2 + dr2[j][w0+c]; thread t handles j = t (float4 per thread)
    const float4 v  = *(const float4*)(dr2 + (b * H + t) * W + w0);
    const float fj  = (float)t;
    const float fj2 = fj * fj;              // exact (< 2^24)
    s_q[0][t] = fj2 + v.x;
    s_q[1][t] = fj2 + v.y;
    s_q[2][t] = fj2 + v.z;
    s_q[3][t] = fj2 + v.w;
    __syncthreads();

    const int lane = t & 63;
    const int wv   = t >> 6;
    const float i0f = (float)lane,         i1f = (float)(lane + 64);
    const float i2f = (float)(lane + 128), i3f = (float)(lane + 192);
    const float n0 = -2.0f * i0f, n1 = -2.0f * i1f;
    const float n2 = -2.0f * i2f, n3 = -2.0f * i3f;
    float b0 = 4e12f, b1 = 4e12f, b2 = 4e12f, b3 = 4e12f;

    float fjv = 0.0f;
    #pragma unroll 4
    for (int jv = 0; jv < 64; ++jv, fjv += 4.0f) {
        const float4 m = *(const float4*)&s_q[wv][jv << 2];
        upd16(m, fjv, n0, n1, n2, n3, b0, b1, b2, b3);
    }

    const int wcol = w0 + wv;
    const int base = (b * H + lane) * W + wcol;
    float acc;
    {
        const float dist = sqrtf(fmaf(i0f, i0f, b0));
        const float x = logits[base];
        acc = dist / (1.0f + expf(-x));
    }
    {
        const float dist = sqrtf(fmaf(i1f, i1f, b1));
        const float x = logits[base + 64 * W];
        acc += dist / (1.0f + expf(-x));
    }
    {
        const float dist = sqrtf(fmaf(i2f, i2f, b2));
        const float x = logits[base + 128 * W];
        acc += dist / (1.0f + expf(-x));
    }
    {
        const float dist = sqrtf(fmaf(i3f, i3f, b3));
        const float x = logits[base + 192 * W];
        acc += dist / (1.0f + expf(-x));
    }

    const float s = block_reduce_sum_256(acc);
    if (t == 0) partials[blockIdx.x] = s;
}

__global__ __launch_bounds__(256) void final_reduce_kernel(
        const float* __restrict__ partials, float* __restrict__ out,
        int n, float scale) {
    float v = 0.0f;
    for (int idx = threadIdx.x; idx < n; idx += 256)
        v += partials[idx];
    v = block_reduce_sum_256(v);
    if (threadIdx.x == 0) out[0] = v * scale;
}

extern "C" void kernel_launch(void* const* d_in, const int* in_sizes, int n_in,
                              void* d_out, int out_size, void* d_ws, size_t ws_size,
                              hipStream_t stream) {
    const float* logits = (const float*)d_in[0];
    const int*   target = (const int*)d_in[1];

    float* dr2      = (float*)d_ws;     // NPIX floats (2 MB)
    float* partials = dr2 + NPIX;       // 512 floats

    row_dist_kernel<<<B * H / 4, 256, 0, stream>>>(target, dr2);
    col_pass_kernel<<<B * W / 4, 256, 0, stream>>>(logits, dr2, partials);
    final_reduce_kernel<<<1, 256, 0, stream>>>(partials, (float*)d_out,
                                               B * W / 4, 1.0f / (float)NPIX);
}